// Round 9
// baseline (2410.664 us; speedup 1.0000x reference)
//
#include <hip/hip_runtime.h>
#include <hip/hip_bf16.h>
#include <stdint.h>

// LSTM: T=512, B=64, D=1024, H=1024, gates order i,f,g,o
#define T_STEPS 512
#define BATCH   64
#define DIM     1024
#define HID     1024
#define NG      4096                 // 4*HID
#define MROWS   (T_STEPS * BATCH)    // 32768

typedef __bf16 bf16;
typedef __bf16 bf16x4 __attribute__((ext_vector_type(4)));
typedef __bf16 bf16x8 __attribute__((ext_vector_type(8)));
typedef float  f32x4  __attribute__((ext_vector_type(4)));
typedef unsigned int u32;
typedef u32 u32x2 __attribute__((ext_vector_type(2)));
typedef u32 u32x4 __attribute__((ext_vector_type(4)));

__device__ __forceinline__ void g2lds16(const void* g, void* l) {
    __builtin_amdgcn_global_load_lds(
        (const __attribute__((address_space(1))) void*)g,
        (__attribute__((address_space(3))) void*)l, 16, 0, 0);
}

__device__ __forceinline__ float fsigmoid(float x) {
    return 1.0f / (1.0f + __expf(-x));   // safe at +-inf
}
__device__ __forceinline__ float ftanh_(float x) {
    return 1.0f - 2.0f / (__expf(2.0f * x) + 1.0f);   // safe at +-inf
}

// ---- LLC-coherent (bypass L1+L2) ops: proven in R2/R3/R8 flag protocol ----
__device__ __forceinline__ u32x4 load16_cc(const void* p) {
    u32x4 r;
    asm volatile("global_load_dwordx4 %0, %1, off sc0 sc1" : "=v"(r) : "v"(p) : "memory");
    return r;
}
__device__ __forceinline__ u32 ld4_cc(const u32* p) {
    u32 r;
    asm volatile("global_load_dword %0, %1, off sc0 sc1" : "=v"(r) : "v"(p) : "memory");
    return r;
}
__device__ __forceinline__ void store2_cc(void* p, u32 v) {
    asm volatile("global_store_short %0, %1, off sc0 sc1" :: "v"(p), "v"(v) : "memory");
}
__device__ __forceinline__ void st4_cc(u32* p, u32 v) {
    asm volatile("global_store_dword %0, %1, off sc0 sc1" :: "v"(p), "v"(v) : "memory");
}
__device__ __forceinline__ u32x2 load8_cached(const void* p) {
    u32x2 r;
    asm volatile("global_load_dwordx2 %0, %1, off" : "=v"(r) : "v"(p) : "memory");
    return r;
}
__device__ __forceinline__ void store4_f32(float* p, float v) {
    asm volatile("global_store_dword %0, %1, off" :: "v"(p), "v"(v) : "memory");
}
#define WAITVM(n) asm volatile("s_waitcnt vmcnt(" #n ")" ::: "memory")

// ---------------------------------------------------------------------------
// prep: fp32->bf16 conversions, W_ih column-permute (n' = (n&1023)*4 + (n>>10)),
// W_hh scatter into MFMA-fragment order (wfrag), bias sum (permuted),
// zero h0 buffer and per-wave barrier flags (re-zeroed every launch).
// ---------------------------------------------------------------------------
__global__ __launch_bounds__(256) void prep_kernel(
    const float* __restrict__ x,   const float* __restrict__ wih,
    const float* __restrict__ whh, const float* __restrict__ bih,
    const float* __restrict__ bhh,
    bf16* __restrict__ xb, bf16* __restrict__ wihp, bf16* __restrict__ wfrag,
    float* __restrict__ bsump, bf16* __restrict__ hbuf, u32* __restrict__ flags)
{
    const int nt  = gridDim.x * blockDim.x;
    const int gid = blockIdx.x * blockDim.x + threadIdx.x;

    for (int i = gid; i < MROWS * DIM / 4; i += nt) {
        f32x4 v = *(const f32x4*)(x + (size_t)i * 4);
        bf16x4 o = {(bf16)v[0], (bf16)v[1], (bf16)v[2], (bf16)v[3]};
        *(bf16x4*)(xb + (size_t)i * 4) = o;
    }
    for (int i = gid; i < NG * (DIM / 4); i += nt) {
        const int n = i >> 8, c4 = (i & 255) * 4;
        f32x4 v = *(const f32x4*)(wih + (size_t)n * DIM + c4);
        bf16x4 o = {(bf16)v[0], (bf16)v[1], (bf16)v[2], (bf16)v[3]};
        const int np = ((n & 1023) << 2) | (n >> 10);
        *(bf16x4*)(wihp + (size_t)np * DIM + c4) = o;
    }
    // wfrag: element i = ((hg*4 + wv)*64 + f)*64 + lane, f = kk*8+n;
    // grow = (lane&3)*1024 + hg*32 + n*4 + ((lane&15)>>2), k0 = wv*256+kk*32+(lane>>4)*8
    for (int i = gid; i < NG * HID / 8; i += nt) {
        const int lane = i & 63;
        const int f    = (i >> 6) & 63;
        const int wv   = (i >> 12) & 3;
        const int hg   = i >> 14;
        const int n = f & 7, kk = f >> 3;
        const int grow = (lane & 3) * 1024 + hg * 32 + n * 4 + ((lane & 15) >> 2);
        const int k0   = wv * 256 + kk * 32 + (lane >> 4) * 8;
        f32x4 v0 = *(const f32x4*)(whh + (size_t)grow * HID + k0);
        f32x4 v1 = *(const f32x4*)(whh + (size_t)grow * HID + k0 + 4);
        bf16x8 o = {(bf16)v0[0], (bf16)v0[1], (bf16)v0[2], (bf16)v0[3],
                    (bf16)v1[0], (bf16)v1[1], (bf16)v1[2], (bf16)v1[3]};
        *(bf16x8*)(wfrag + (size_t)i * 8) = o;
    }
    for (int i = gid; i < NG; i += nt)
        bsump[((i & 1023) << 2) | (i >> 10)] = bih[i] + bhh[i];
    for (int i = gid; i < BATCH * HID / 4; i += nt) {
        bf16x4 z = {(bf16)0.f, (bf16)0.f, (bf16)0.f, (bf16)0.f};
        *(bf16x4*)(hbuf + (size_t)i * 4) = z;   // h[buf 0] = 0
    }
    for (int i = gid; i < 256 * 4 * 16; i += nt)
        flags[i] = 0u;
}

// ---------------------------------------------------------------------------
// xg GEMM: C[32768,4096] = xb[32768,1024] @ wihp^T + bsump, bf16 out.
// ---------------------------------------------------------------------------
__global__ __launch_bounds__(256) void gemm_kernel(
    const bf16* __restrict__ A, const bf16* __restrict__ B,
    const float* __restrict__ bsum, bf16* __restrict__ xgp)
{
    __shared__ char lds[16384];
    char* As = lds;
    char* Bs = lds + 8192;

    const int tid  = threadIdx.x;
    const int lane = tid & 63;
    const int wv   = tid >> 6;
    const int wr   = wv >> 1, wc = wv & 1;
    const int bx   = blockIdx.x & 31;   // N tile
    const int by   = blockIdx.x >> 5;   // M tile
    const int m0   = by * 128, n0 = bx * 128;

    f32x4 acc[4][4] = {};

    const int r4 = tid >> 2;
    const int c8 = (tid & 3) * 8;
    const size_t arow0 = (size_t)(m0 +      r4) * DIM + c8;
    const size_t arow1 = (size_t)(m0 + 64 + r4) * DIM + c8;
    const size_t brow0 = (size_t)(n0 +      r4) * DIM + c8;
    const size_t brow1 = (size_t)(n0 + 64 + r4) * DIM + c8;
    const int ldsoff = tid * 16;

    for (int k0 = 0; k0 < DIM; k0 += 32) {
        g2lds16(A + arow0 + k0, As + ldsoff);
        g2lds16(A + arow1 + k0, As + 4096 + ldsoff);
        g2lds16(B + brow0 + k0, Bs + ldsoff);
        g2lds16(B + brow1 + k0, Bs + 4096 + ldsoff);
        __syncthreads();

        bf16x8 af[4], bfr[4];
        #pragma unroll
        for (int i = 0; i < 4; ++i) {
            af[i]  = *(const bf16x8*)(As + (wr*64 + i*16 + (lane & 15))*64 + (lane >> 4)*16);
            bfr[i] = *(const bf16x8*)(Bs + (wc*64 + i*16 + (lane & 15))*64 + (lane >> 4)*16);
        }
        #pragma unroll
        for (int i = 0; i < 4; ++i)
            #pragma unroll
            for (int j = 0; j < 4; ++j)
                acc[i][j] = __builtin_amdgcn_mfma_f32_16x16x32_bf16(
                    af[i], bfr[j], acc[i][j], 0, 0, 0);
        __syncthreads();
    }

    #pragma unroll
    for (int j = 0; j < 4; ++j) {
        const int nn = n0 + wc*64 + j*16 + (lane & 15);
        const float bias = bsum[nn];
        #pragma unroll
        for (int i = 0; i < 4; ++i) {
            #pragma unroll
            for (int r = 0; r < 4; ++r) {
                const int mm = m0 + wr*64 + i*16 + ((lane >> 4) << 2) + r;
                xgp[(size_t)mm * NG + nn] = (bf16)(acc[i][j][r] + bias);
            }
        }
    }
}

// ---------------------------------------------------------------------------
// Persistent recurrent kernel, flag protocol with PER-WAVE flags + pipelined
// poll. 256 WGs = 8 bg x 32 hg. flag[(X,q)]=t+1 certifies: wave q of X
// finished reading h[t] AND its h[t+1] rows {2q,2q+1} are acked at LLC.
// Consumer wave wv polls 8 producer WGs x 4 waves = 32 flags (one per lane).
// Overwrite-safety: E(t+1) overwrites buffer holding h[t]; it follows the
// D(t+1) syncthreads, which joins all 4 waves' A(t+1) polls whose union is
// ALL 128 flags(bg) >= t+1 => every wave of every WG finished B(t) reads.
// gbuf is parity-doubled (wave skew without the old E-syncthreads).
// Pipelined poll: E issues next step's poll (asm) after the h-store;
// WAITVM(1) acks only the h-store (in-order vmcnt, validated by R8's
// passing vmcnt(2)); A(t+1) does WAITVM(3) (poll oldest of [poll,flag,out,
// xg]) + volatile identity-asm on the poll register so the compare cannot
// be hoisted above the wait (R6/R7 lesson). All counted-window VMEM is
// inline asm so compiler-placed ops cannot corrupt the counts.
// ---------------------------------------------------------------------------
__global__ __launch_bounds__(256, 1) void lstm_kernel(
    const bf16* __restrict__ xgp, const bf16* __restrict__ wfrag,
    bf16* __restrict__ hbuf, u32* __restrict__ flags, float* __restrict__ out)
{
    __shared__ float gbuf[2][4][8][136];   // [parity][wave][batch row][gate col]

    const int tid  = threadIdx.x;
    const int lane = tid & 63;
    const int wv   = tid >> 6;
    const int wg   = blockIdx.x;
    const int hg   = wg & 31;
    const int bg   = wg >> 5;

    // W fragments -> 256 regs/lane (64 x bf16x8), coalesced 16B loads
    bf16x8 wreg[64];
    {
        const bf16* wb = wfrag + ((size_t)(hg * 4 + wv) * 4096 + lane) * 8;
        #pragma unroll
        for (int f = 0; f < 64; ++f)
            wreg[f] = *(const bf16x8*)(wb + (size_t)f * 512);
    }

    const int frow  = lane & 15;
    const int hrow  = bg * 8 + (frow & 7);            // row-clamp dedup
    const int kbase = wv * 256 + (lane >> 4) * 8;
    const int b_el  = tid >> 5;                       // 0..7
    const int j_el  = tid & 31;                       // 0..31
    const int hid   = hg * 32 + j_el;

    // per-wave flags: idx = ((bg*32 + hg)*4 + wave) * 16 (64B spacing)
    const u32* pollp = flags
        + ((size_t)((bg * 32 + wv * 8 + (lane & 7)) * 4 + ((lane >> 3) & 3)) << 4);
    u32* myflag = flags + ((size_t)((bg * 32 + hg) * 4 + wv) << 4);

    float c = 0.f;
    u32 pollv = 0u;
    // xg[0] (permuted layout: 4 gates of `hid` contiguous)
    u32x2 xr = load8_cached(xgp + (size_t)(bg * 8 + b_el) * NG + hid * 4);

    #pragma unroll 1
    for (int step = 0; step < T_STEPS; ++step) {
        // A: check pipelined poll result; retry via atomic loads if not ready
        if (step > 0) {
            WAITVM(3);                               // poll (oldest) retired
            asm volatile("" : "+v"(pollv));          // pin compare after the wait
            if (!__all((int)(pollv >= (u32)step))) {
                do {
                    __builtin_amdgcn_s_sleep(1);
                    pollv = __hip_atomic_load(pollp, __ATOMIC_RELAXED,
                                              __HIP_MEMORY_SCOPE_AGENT);
                } while (!__all((int)(pollv >= (u32)step)));
            }
        }

        // B: h fragment loads (LLC-coherent); vmcnt(0) also drains prior
        // flag/out/xg (older ops, overlapped -> no extra cost)
        const bf16* hb = hbuf + (step & 1) * (BATCH * HID) + (size_t)hrow * HID + kbase;
        u32x4 afr[8];
        #pragma unroll
        for (int kk = 0; kk < 8; ++kk)
            afr[kk] = load16_cc(hb + kk * 32);
        WAITVM(0);
        __builtin_amdgcn_sched_barrier(0);

        // C: MFMA, 8 gate N-tiles over this wave's K quarter (B from VGPR)
        f32x4 acc[8] = {};
        #pragma unroll
        for (int kk = 0; kk < 8; ++kk) {
            bf16x8 a = __builtin_bit_cast(bf16x8, afr[kk]);
            #pragma unroll
            for (int n = 0; n < 8; ++n)
                acc[n] = __builtin_amdgcn_mfma_f32_16x16x32_bf16(
                    a, wreg[kk * 8 + n], acc[n], 0, 0, 0);
        }

        // D: cross-wave reduce staging (parity-doubled), one syncthreads
        const int pp = step & 1;
        if (lane < 32) {
            const int q = lane >> 4;
            #pragma unroll
            for (int n = 0; n < 8; ++n)
                #pragma unroll
                for (int r = 0; r < 4; ++r)
                    gbuf[pp][wv][q * 4 + r][n * 16 + frow] = acc[n][r];
        }
        __syncthreads();

        // E: elementwise; h-store; pipelined poll issue; ack; flag; out; xg
        bf16x4 xv = __builtin_bit_cast(bf16x4, xr);
        float P[4];
        #pragma unroll
        for (int g = 0; g < 4; ++g)
            P[g] = gbuf[pp][0][b_el][j_el * 4 + g] + gbuf[pp][1][b_el][j_el * 4 + g]
                 + gbuf[pp][2][b_el][j_el * 4 + g] + gbuf[pp][3][b_el][j_el * 4 + g]
                 + (float)xv[g];
        const float ig = fsigmoid(P[0]);
        const float fg = fsigmoid(P[1]);
        const float gg = ftanh_(P[2]);
        const float og = fsigmoid(P[3]);
        c = fg * c + ig * gg;
        const float hv = og * ftanh_(c);

        const bf16 h16 = (bf16)hv;
        store2_cc(hbuf + ((step & 1) ^ 1) * (BATCH * HID)
                       + (size_t)(bg * 8 + b_el) * HID + hid,
                  (u32)__builtin_bit_cast(unsigned short, h16));   // o1
        pollv = ld4_cc(pollp);                                      // o2 (next step)
        WAITVM(1);                         // h-store (oldest) acked at LLC
        __builtin_amdgcn_sched_barrier(0);
        if (lane == 0)
            st4_cc(myflag, (u32)(step + 1));                        // o3
        store4_f32(out + (size_t)(step * BATCH + bg * 8 + b_el) * HID + hid, hv); // o4
        if (step + 1 < T_STEPS)
            xr = load8_cached(xgp + ((size_t)((step + 1) * BATCH) + bg * 8 + b_el) * NG
                                  + hid * 4);                       // o5
    }
}

// ---------------------------------------------------------------------------
extern "C" void kernel_launch(void* const* d_in, const int* in_sizes, int n_in,
                              void* d_out, int out_size, void* d_ws, size_t ws_size,
                              hipStream_t stream) {
    const float* x   = (const float*)d_in[0];   // [512,64,1024]
    const float* wih = (const float*)d_in[1];   // [4096,1024]
    const float* whh = (const float*)d_in[2];   // [4096,1024]
    const float* bih = (const float*)d_in[3];   // [4096]
    const float* bhh = (const float*)d_in[4];   // [4096]
    float* out = (float*)d_out;                 // [512,64,1024]

    char* ws = (char*)d_ws;
    size_t off = 0;
    bf16* xgp   = (bf16*)(ws + off); off += (size_t)MROWS * NG * 2;      // 256 MB
    bf16* xb    = (bf16*)(ws + off); off += (size_t)MROWS * DIM * 2;     //  64 MB
    bf16* wihp  = (bf16*)(ws + off); off += (size_t)NG * DIM * 2;        //   8 MB
    bf16* wfrag = (bf16*)(ws + off); off += (size_t)NG * HID * 2;        //   8 MB
    float* bsum = (float*)(ws + off); off += (size_t)NG * 4;             //  16 KB
    bf16* hbuf  = (bf16*)(ws + off); off += (size_t)2 * BATCH * HID * 2; // 256 KB
    u32* flags  = (u32*)(ws + off); off += 256 * 4 * 16 * 4;             //  64 KB
    (void)ws_size; (void)in_sizes; (void)n_in; (void)out_size;

    prep_kernel<<<2048, 256, 0, stream>>>(x, wih, whh, bih, bhh,
                                          xb, wihp, wfrag, bsum, hbuf, flags);
    gemm_kernel<<<8192, 256, 0, stream>>>(xb, wihp, bsum, xgp);
    lstm_kernel<<<256, 256, 0, stream>>>(xgp, wfrag, hbuf, flags, out);
}

// Round 10
// 1944.351 us; speedup vs baseline: 1.2398x; 1.2398x over previous
//
#include <hip/hip_runtime.h>
#include <hip/hip_bf16.h>
#include <stdint.h>

// LSTM: T=512, B=64, D=1024, H=1024, gates order i,f,g,o
#define T_STEPS 512
#define BATCH   64
#define DIM     1024
#define HID     1024
#define NG      4096                 // 4*HID
#define MROWS   (T_STEPS * BATCH)    // 32768

typedef __bf16 bf16;
typedef __bf16 bf16x4 __attribute__((ext_vector_type(4)));
typedef __bf16 bf16x8 __attribute__((ext_vector_type(8)));
typedef float  f32x4  __attribute__((ext_vector_type(4)));
typedef unsigned int u32;
typedef u32 u32x2 __attribute__((ext_vector_type(2)));
typedef u32 u32x4 __attribute__((ext_vector_type(4)));

__device__ __forceinline__ void g2lds16(const void* g, void* l) {
    __builtin_amdgcn_global_load_lds(
        (const __attribute__((address_space(1))) void*)g,
        (__attribute__((address_space(3))) void*)l, 16, 0, 0);
}

__device__ __forceinline__ float fsigmoid(float x) {
    return 1.0f / (1.0f + __expf(-x));   // safe at +-inf
}
__device__ __forceinline__ float ftanh_(float x) {
    return 1.0f - 2.0f / (__expf(2.0f * x) + 1.0f);   // safe at +-inf
}

// ---- LLC-coherent (bypass L1+L2) ops: proven in R2/R3/R8 flag protocol ----
__device__ __forceinline__ u32x4 load16_cc(const void* p) {
    u32x4 r;
    asm volatile("global_load_dwordx4 %0, %1, off sc0 sc1" : "=v"(r) : "v"(p) : "memory");
    return r;
}
__device__ __forceinline__ void store2_cc(void* p, u32 v) {
    asm volatile("global_store_short %0, %1, off sc0 sc1" :: "v"(p), "v"(v) : "memory");
}
__device__ __forceinline__ u32x2 load8_cached(const void* p) {
    u32x2 r;
    asm volatile("global_load_dwordx2 %0, %1, off" : "=v"(r) : "v"(p) : "memory");
    return r;
}
__device__ __forceinline__ void store4_f32(float* p, float v) {
    asm volatile("global_store_dword %0, %1, off" :: "v"(p), "v"(v) : "memory");
}
#define WAITVM(n) asm volatile("s_waitcnt vmcnt(" #n ")" ::: "memory")

// ---------------------------------------------------------------------------
// prep: fp32->bf16 conversions, W_ih column-permute (n' = (n&1023)*4 + (n>>10)),
// W_hh scatter into MFMA-fragment order (wfrag), bias sum (permuted),
// zero h0 buffer and barrier flags (re-zeroed every launch => replay-safe).
// ---------------------------------------------------------------------------
__global__ __launch_bounds__(256) void prep_kernel(
    const float* __restrict__ x,   const float* __restrict__ wih,
    const float* __restrict__ whh, const float* __restrict__ bih,
    const float* __restrict__ bhh,
    bf16* __restrict__ xb, bf16* __restrict__ wihp, bf16* __restrict__ wfrag,
    float* __restrict__ bsump, bf16* __restrict__ hbuf, u32* __restrict__ flags)
{
    const int nt  = gridDim.x * blockDim.x;
    const int gid = blockIdx.x * blockDim.x + threadIdx.x;

    for (int i = gid; i < MROWS * DIM / 4; i += nt) {
        f32x4 v = *(const f32x4*)(x + (size_t)i * 4);
        bf16x4 o = {(bf16)v[0], (bf16)v[1], (bf16)v[2], (bf16)v[3]};
        *(bf16x4*)(xb + (size_t)i * 4) = o;
    }
    for (int i = gid; i < NG * (DIM / 4); i += nt) {
        const int n = i >> 8, c4 = (i & 255) * 4;
        f32x4 v = *(const f32x4*)(wih + (size_t)n * DIM + c4);
        bf16x4 o = {(bf16)v[0], (bf16)v[1], (bf16)v[2], (bf16)v[3]};
        const int np = ((n & 1023) << 2) | (n >> 10);
        *(bf16x4*)(wihp + (size_t)np * DIM + c4) = o;
    }
    // wfrag: element i = ((hg*4 + wv)*64 + f)*64 + lane, f = kk*8+n;
    // grow = (lane&3)*1024 + hg*32 + n*4 + ((lane&15)>>2), k0 = wv*256+kk*32+(lane>>4)*8
    for (int i = gid; i < NG * HID / 8; i += nt) {
        const int lane = i & 63;
        const int f    = (i >> 6) & 63;
        const int wv   = (i >> 12) & 3;
        const int hg   = i >> 14;
        const int n = f & 7, kk = f >> 3;
        const int grow = (lane & 3) * 1024 + hg * 32 + n * 4 + ((lane & 15) >> 2);
        const int k0   = wv * 256 + kk * 32 + (lane >> 4) * 8;
        f32x4 v0 = *(const f32x4*)(whh + (size_t)grow * HID + k0);
        f32x4 v1 = *(const f32x4*)(whh + (size_t)grow * HID + k0 + 4);
        bf16x8 o = {(bf16)v0[0], (bf16)v0[1], (bf16)v0[2], (bf16)v0[3],
                    (bf16)v1[0], (bf16)v1[1], (bf16)v1[2], (bf16)v1[3]};
        *(bf16x8*)(wfrag + (size_t)i * 8) = o;
    }
    for (int i = gid; i < NG; i += nt)
        bsump[((i & 1023) << 2) | (i >> 10)] = bih[i] + bhh[i];
    for (int i = gid; i < BATCH * HID / 4; i += nt) {
        bf16x4 z = {(bf16)0.f, (bf16)0.f, (bf16)0.f, (bf16)0.f};
        *(bf16x4*)(hbuf + (size_t)i * 4) = z;   // h[buf 0] = 0
    }
    for (int i = gid; i < 256 * 16; i += nt)
        flags[i] = 0u;
}

// ---------------------------------------------------------------------------
// xg GEMM: C[32768,4096] = xb[32768,1024] @ wihp^T + bsump, bf16 out.
// ---------------------------------------------------------------------------
__global__ __launch_bounds__(256) void gemm_kernel(
    const bf16* __restrict__ A, const bf16* __restrict__ B,
    const float* __restrict__ bsum, bf16* __restrict__ xgp)
{
    __shared__ char lds[16384];
    char* As = lds;
    char* Bs = lds + 8192;

    const int tid  = threadIdx.x;
    const int lane = tid & 63;
    const int wv   = tid >> 6;
    const int wr   = wv >> 1, wc = wv & 1;
    const int bx   = blockIdx.x & 31;   // N tile
    const int by   = blockIdx.x >> 5;   // M tile
    const int m0   = by * 128, n0 = bx * 128;

    f32x4 acc[4][4] = {};

    const int r4 = tid >> 2;
    const int c8 = (tid & 3) * 8;
    const size_t arow0 = (size_t)(m0 +      r4) * DIM + c8;
    const size_t arow1 = (size_t)(m0 + 64 + r4) * DIM + c8;
    const size_t brow0 = (size_t)(n0 +      r4) * DIM + c8;
    const size_t brow1 = (size_t)(n0 + 64 + r4) * DIM + c8;
    const int ldsoff = tid * 16;

    for (int k0 = 0; k0 < DIM; k0 += 32) {
        g2lds16(A + arow0 + k0, As + ldsoff);
        g2lds16(A + arow1 + k0, As + 4096 + ldsoff);
        g2lds16(B + brow0 + k0, Bs + ldsoff);
        g2lds16(B + brow1 + k0, Bs + 4096 + ldsoff);
        __syncthreads();

        bf16x8 af[4], bfr[4];
        #pragma unroll
        for (int i = 0; i < 4; ++i) {
            af[i]  = *(const bf16x8*)(As + (wr*64 + i*16 + (lane & 15))*64 + (lane >> 4)*16);
            bfr[i] = *(const bf16x8*)(Bs + (wc*64 + i*16 + (lane & 15))*64 + (lane >> 4)*16);
        }
        #pragma unroll
        for (int i = 0; i < 4; ++i)
            #pragma unroll
            for (int j = 0; j < 4; ++j)
                acc[i][j] = __builtin_amdgcn_mfma_f32_16x16x32_bf16(
                    af[i], bfr[j], acc[i][j], 0, 0, 0);
        __syncthreads();
    }

    #pragma unroll
    for (int j = 0; j < 4; ++j) {
        const int nn = n0 + wc*64 + j*16 + (lane & 15);
        const float bias = bsum[nn];
        #pragma unroll
        for (int i = 0; i < 4; ++i) {
            #pragma unroll
            for (int r = 0; r < 4; ++r) {
                const int mm = m0 + wr*64 + i*16 + ((lane >> 4) << 2) + r;
                xgp[(size_t)mm * NG + nn] = (bf16)(acc[i][j][r] + bias);
            }
        }
    }
}

// ---------------------------------------------------------------------------
// Persistent recurrent kernel — R8's proven flag protocol, with the h read
// path changed from direct LLC loads (32 KB/WG/step, 2x frow-dup + 4x wave
// K-redundancy) to per-wave LDS staging (16 KB/WG/step):
//   B: each wave stages its OWN disjoint quarter (8 rows x its 256-k slice,
//      4 KB) via 4 ld16_cc/lane (proven-coherent), XOR-swizzled ds_write
//      (byte ^= row<<4 -> conflict-free b128 reads). No stage barrier needed:
//      quarters are wave-private (written and read by the same wave).
//   C: MFMA A-frags via ds_read_b128 from LDS (swizzled), B-frags from VGPRs.
// vmcnt discipline: B issues exactly [4 ld16, out-store(t-1), xg(t+1,
// clamped at last step -> constant op count)] -> WAITVM(2) completes exactly
// the 4 h-loads (also fixes R8's latent last-step count bug). LDS writes
// placed after WAITVM+sched_barrier (memory-clobber pins them). Flags, W
// fragments, gbuf reduce, elementwise, E-tail: R8 verbatim.
// ---------------------------------------------------------------------------
__global__ __launch_bounds__(256, 1) void lstm_kernel(
    const bf16* __restrict__ xgp, const bf16* __restrict__ wfrag,
    bf16* __restrict__ hbuf, u32* __restrict__ flags, float* __restrict__ out)
{
    __shared__ char  hstage[8 * 2048];  // h[8 rows][1024 k] bf16, XOR-swizzled
    __shared__ float gbuf[4][8][136];   // [wave][batch row][gate col]

    const int tid  = threadIdx.x;
    const int lane = tid & 63;
    const int wv   = tid >> 6;
    const int wg   = blockIdx.x;
    const int hg   = wg & 31;
    const int bg   = wg >> 5;

    // W fragments -> 256 regs/lane (64 x bf16x8), coalesced 16B loads
    bf16x8 wreg[64];
    {
        const bf16* wb = wfrag + ((size_t)(hg * 4 + wv) * 4096 + lane) * 8;
        #pragma unroll
        for (int f = 0; f < 64; ++f)
            wreg[f] = *(const bf16x8*)(wb + (size_t)f * 512);
    }

    const int frow  = lane & 15;
    const int b_el  = tid >> 5;                       // 0..7
    const int j_el  = tid & 31;                       // 0..31
    const int hid   = hg * 32 + j_el;

    // staging: wave wv owns bytes [row*2048 + wv*512, +512) for rows 0..7.
    // chunk c = cl*64 + lane: row = cl*2 + (lane>>5), off = (lane&31)*16.
    const int srow0 = lane >> 5;                      // +cl*2
    const int soff  = (lane & 31) * 16;
    // read: logical byte = r*2048 + wv*512 + (lane>>4)*16 + kk*64, XOR r<<4
    const int rbase = frow & 7;
    const int cbase = rbase * 2048 + wv * 512 + (lane >> 4) * 16;
    const int rxor  = rbase << 4;

    const u32* pollp = flags + ((bg * 32 + wv * 8 + (lane & 7)) << 4);
    u32* myflag      = flags + ((bg * 32 + hg) << 4);

    float c = 0.f;
    float hv_prev = 0.f;
    u32x2 xr = load8_cached(xgp + (size_t)(bg * 8 + b_el) * NG + hid * 4);

    #pragma unroll 1
    for (int step = 0; step < T_STEPS; ++step) {
        // A: per-wave poll of this wave's 8 producers (h[step] stored+acked)
        while (__hip_atomic_load(pollp, __ATOMIC_RELAXED,
                                 __HIP_MEMORY_SCOPE_AGENT) < (u32)step)
            __builtin_amdgcn_s_sleep(1);

        // B: issue exactly 6 VMEM ops: 4 h-quarter loads, out(t-1), xg(next)
        const char* hbp = (const char*)(hbuf + (step & 1) * (BATCH * HID)
                                             + (size_t)(bg * 8) * HID);
        u32x4 sv[4];
        #pragma unroll
        for (int cl = 0; cl < 4; ++cl) {
            const int row_s = cl * 2 + srow0;
            sv[cl] = load16_cc(hbp + row_s * 2048 + wv * 512 + soff);
        }
        const int orow = (step == 0) ? 0 : step - 1;
        store4_f32(out + (size_t)(orow * BATCH + bg * 8 + b_el) * HID + hid, hv_prev);
        const int nx = (step + 1 < T_STEPS) ? step + 1 : step;   // clamp: const op count
        u32x2 xr_n = load8_cached(xgp + ((size_t)(nx * BATCH) + bg * 8 + b_el) * NG
                                      + hid * 4);
        WAITVM(2);                         // exactly the 4 h-loads complete
        __builtin_amdgcn_sched_barrier(0);

        // stage into LDS (wave-private quarter, XOR-swizzled)
        #pragma unroll
        for (int cl = 0; cl < 4; ++cl) {
            const int row_s = cl * 2 + srow0;
            *(u32x4*)(hstage + ((row_s * 2048 + wv * 512 + soff) ^ (row_s << 4)))
                = sv[cl];
        }

        // C: A-frags from LDS (swizzled b128 reads), MFMA 8 gate N-tiles
        bf16x8 af[8];
        #pragma unroll
        for (int kk = 0; kk < 8; ++kk)
            af[kk] = *(const bf16x8*)(hstage + ((cbase + kk * 64) ^ rxor));
        f32x4 acc[8] = {};
        #pragma unroll
        for (int kk = 0; kk < 8; ++kk) {
            #pragma unroll
            for (int n = 0; n < 8; ++n)
                acc[n] = __builtin_amdgcn_mfma_f32_16x16x32_bf16(
                    af[kk], wreg[kk * 8 + n], acc[n], 0, 0, 0);
        }

        // D: cross-wave reduce staging (valid batch rows live in lanes 0..31)
        if (lane < 32) {
            const int q = lane >> 4;
            #pragma unroll
            for (int n = 0; n < 8; ++n)
                #pragma unroll
                for (int r = 0; r < 4; ++r)
                    gbuf[wv][q * 4 + r][n * 16 + frow] = acc[n][r];
        }
        __syncthreads();

        // E: elementwise (one thread per (batch row, hid unit))
        bf16x4 xv = __builtin_bit_cast(bf16x4, xr);
        float P[4];
        #pragma unroll
        for (int g = 0; g < 4; ++g)
            P[g] = gbuf[0][b_el][j_el * 4 + g] + gbuf[1][b_el][j_el * 4 + g]
                 + gbuf[2][b_el][j_el * 4 + g] + gbuf[3][b_el][j_el * 4 + g]
                 + (float)xv[g];
        const float ig = fsigmoid(P[0]);
        const float fg = fsigmoid(P[1]);
        const float gg = ftanh_(P[2]);
        const float og = fsigmoid(P[3]);
        c = fg * c + ig * gg;
        const float hv = og * ftanh_(c);

        const bf16 h16 = (bf16)hv;
        store2_cc(hbuf + ((step & 1) ^ 1) * (BATCH * HID)
                       + (size_t)(bg * 8 + b_el) * HID + hid,
                  (u32)__builtin_bit_cast(unsigned short, h16));
        WAITVM(0);                        // h-store acked at LLC (others already done)
        __builtin_amdgcn_sched_barrier(0);
        __syncthreads();                  // all waves of this WG acked
        if (tid == 0)
            __hip_atomic_store(myflag, (u32)(step + 1),
                               __ATOMIC_RELAXED, __HIP_MEMORY_SCOPE_AGENT);
        hv_prev = hv;
        xr = xr_n;
    }

    // epilogue: final out row
    store4_f32(out + (size_t)((T_STEPS - 1) * BATCH + bg * 8 + b_el) * HID + hid,
               hv_prev);
}

// ---------------------------------------------------------------------------
extern "C" void kernel_launch(void* const* d_in, const int* in_sizes, int n_in,
                              void* d_out, int out_size, void* d_ws, size_t ws_size,
                              hipStream_t stream) {
    const float* x   = (const float*)d_in[0];   // [512,64,1024]
    const float* wih = (const float*)d_in[1];   // [4096,1024]
    const float* whh = (const float*)d_in[2];   // [4096,1024]
    const float* bih = (const float*)d_in[3];   // [4096]
    const float* bhh = (const float*)d_in[4];   // [4096]
    float* out = (float*)d_out;                 // [512,64,1024]

    char* ws = (char*)d_ws;
    size_t off = 0;
    bf16* xgp   = (bf16*)(ws + off); off += (size_t)MROWS * NG * 2;      // 256 MB
    bf16* xb    = (bf16*)(ws + off); off += (size_t)MROWS * DIM * 2;     //  64 MB
    bf16* wihp  = (bf16*)(ws + off); off += (size_t)NG * DIM * 2;        //   8 MB
    bf16* wfrag = (bf16*)(ws + off); off += (size_t)NG * HID * 2;        //   8 MB
    float* bsum = (float*)(ws + off); off += (size_t)NG * 4;             //  16 KB
    bf16* hbuf  = (bf16*)(ws + off); off += (size_t)2 * BATCH * HID * 2; // 256 KB
    u32* flags  = (u32*)(ws + off); off += 256 * 16 * 4;                 //  16 KB
    (void)ws_size; (void)in_sizes; (void)n_in; (void)out_size;

    prep_kernel<<<2048, 256, 0, stream>>>(x, wih, whh, bih, bhh,
                                          xb, wihp, wfrag, bsum, hbuf, flags);
    gemm_kernel<<<8192, 256, 0, stream>>>(xb, wihp, bsum, xgp);
    lstm_kernel<<<256, 256, 0, stream>>>(xgp, wfrag, hbuf, flags, out);
}